// Round 2
// baseline (279.724 us; speedup 1.0000x reference)
//
#include <hip/hip_runtime.h>
#include <stdint.h>

#define NE 4096
#define FD 512
#define NCELLS 39
#define NPAIRS 8192
#define KC 128  // output-feature chunk

typedef __attribute__((ext_vector_type(8))) short short8;
typedef __attribute__((ext_vector_type(8))) unsigned short ushort8;
typedef __attribute__((ext_vector_type(4))) float f32x4;

__device__ __forceinline__ unsigned short f2bf(float f) {
  union { float f; uint32_t u; } v; v.f = f;
  uint32_t u = v.u;
  return (unsigned short)((u + 0x7fffu + ((u >> 16) & 1u)) >> 16);  // RNE
}
__device__ __forceinline__ float bf2f(unsigned short b) {
  return __uint_as_float(((uint32_t)b) << 16);
}

__device__ __forceinline__ void async16(const void* g, void* l) {
  __builtin_amdgcn_global_load_lds((const __attribute__((address_space(1))) void*)g,
                                   (__attribute__((address_space(3))) void*)l, 16, 0, 0);
}

// ---- kernel 1: embedding fp32 -> bf16 ----
__global__ __launch_bounds__(256) void conv_e(const float* __restrict__ E,
                                              unsigned short* __restrict__ Ebf) {
  const int i = blockIdx.x * 256 + threadIdx.x;
  const float4 v = ((const float4*)E)[i];
  ushort4 o;
  o.x = f2bf(v.x); o.y = f2bf(v.y); o.z = f2bf(v.z); o.w = f2bf(v.w);
  ((ushort4*)Ebf)[i] = o;
}

// ---- kernel 2: Wt[ci][kout][n] = wl[c,n] * W[n,kout], bf16, transposed ----
__global__ __launch_bounds__(256) void prep_w(const float* __restrict__ W,
                                              const float* __restrict__ wl,
                                              unsigned short* __restrict__ Wt) {
  __shared__ float tile[32][33];
  const int ci = blockIdx.z;
  const int tn = blockIdx.x * 32, tk = blockIdx.y * 32;
  const int tx = threadIdx.x & 31, ty = threadIdx.x >> 5;
  const float* wlr = wl + (size_t)ci * FD;
#pragma unroll
  for (int i = 0; i < 4; i++) {
    int n = tn + ty + i * 8;
    tile[ty + i * 8][tx] = W[(size_t)n * FD + tk + tx] * wlr[n];
  }
  __syncthreads();
  unsigned short* dst = Wt + (size_t)ci * FD * FD;
#pragma unroll
  for (int i = 0; i < 4; i++) {
    int kout = tk + ty + i * 8;
    dst[(size_t)kout * FD + tn + tx] = f2bf(tile[tx][ty + i * 8]);
  }
}

// ---- kernel 3: U[ci][e][kl] = wl[c,kc0+kl] * sum_n Ebf[e,n] * Wt[ci][kc0+kl][n]
// 128(M) x 128(N=KC) tile, BK=32, 4 waves (2x2), 4x4 MFMA 16x16x32 per wave.
__global__ __launch_bounds__(256) void gemm_k(const unsigned short* __restrict__ Ebf,
                                              const unsigned short* __restrict__ Wt,
                                              const float* __restrict__ wl,
                                              unsigned short* __restrict__ U,
                                              int kc0) {
  __shared__ unsigned short As[128 * 32];
  __shared__ unsigned short Bs[128 * 32];
  const int t = threadIdx.x;
  const int ci = blockIdx.y;
  const unsigned short* Ag = Ebf + (size_t)blockIdx.x * 128 * FD;
  const unsigned short* Bg = Wt + (size_t)ci * FD * FD + (size_t)kc0 * FD;

  f32x4 acc[4][4];
#pragma unroll
  for (int i = 0; i < 4; i++)
#pragma unroll
    for (int j = 0; j < 4; j++) acc[i][j] = (f32x4){0.f, 0.f, 0.f, 0.f};

  const int wave = t >> 6, lane = t & 63;
  const int wm = (wave & 1) * 64, wn = (wave >> 1) * 64;
  const int lr = lane & 15, lq = lane >> 4;
  const int idx0 = t, idx1 = 256 + t;
  const int r0 = idx0 >> 2, cb0 = (idx0 & 3) * 8;
  const int r1 = idx1 >> 2, cb1 = (idx1 & 3) * 8;

  for (int k0 = 0; k0 < FD; k0 += 32) {
    async16(Ag + (size_t)r0 * FD + k0 + cb0, &As[idx0 * 8]);
    async16(Ag + (size_t)r1 * FD + k0 + cb1, &As[idx1 * 8]);
    async16(Bg + (size_t)r0 * FD + k0 + cb0, &Bs[idx0 * 8]);
    async16(Bg + (size_t)r1 * FD + k0 + cb1, &Bs[idx1 * 8]);
    __syncthreads();
    short8 af[4], bq[4];
#pragma unroll
    for (int mi = 0; mi < 4; mi++) af[mi] = *(const short8*)&As[(wm + mi * 16 + lr) * 32 + lq * 8];
#pragma unroll
    for (int ni = 0; ni < 4; ni++) bq[ni] = *(const short8*)&Bs[(wn + ni * 16 + lr) * 32 + lq * 8];
#pragma unroll
    for (int mi = 0; mi < 4; mi++)
#pragma unroll
      for (int ni = 0; ni < 4; ni++)
        acc[mi][ni] = __builtin_amdgcn_mfma_f32_16x16x32_bf16(af[mi], bq[ni], acc[mi][ni], 0, 0, 0);
    __syncthreads();
  }

  // epilogue: scale by wl[c, kc0 + nl], store bf16.  C/D: col=lane&15, row=(lane>>4)*4+reg
  const float* wlr = wl + (size_t)ci * FD + kc0;
  unsigned short* Up = U + (size_t)ci * NE * KC;
  float wlv[4];
#pragma unroll
  for (int ni = 0; ni < 4; ni++) wlv[ni] = wlr[wn + ni * 16 + lr];
#pragma unroll
  for (int mi = 0; mi < 4; mi++) {
    int mbase = blockIdx.x * 128 + wm + mi * 16 + lq * 4;
#pragma unroll
    for (int ni = 0; ni < 4; ni++) {
      int nl = wn + ni * 16 + lr;
#pragma unroll
      for (int r = 0; r < 4; r++) {
        Up[(size_t)(mbase + r) * KC + nl] = f2bf(acc[mi][ni][r] * wlv[ni]);
      }
    }
  }
}

// ---- kernel 4: out[c,p] (+)= sum_{kl<KC} U[ci,i0,kl] * Ebf[i1,kc0+kl]
// 16 lanes per pair; 256 pairs per block.
__global__ __launch_bounds__(256) void dot_k(const unsigned short* __restrict__ U,
                                             const unsigned short* __restrict__ Ebf,
                                             const int* __restrict__ index,
                                             float* __restrict__ out,
                                             int kc0, int first) {
  const int ci = blockIdx.y;
  const int wave = threadIdx.x >> 6, lane = threadIdx.x & 63;
  const int sub = lane >> 4, l16 = lane & 15;
  const unsigned short* Uc = U + (size_t)ci * NE * KC;
  const unsigned short* Ec = Ebf + kc0;
  const size_t cp = (size_t)ci * NPAIRS;
  const int pbase = blockIdx.x * 256 + wave * 64 + sub;
#pragma unroll 4
  for (int b = 0; b < 16; b++) {
    const int p = pbase + b * 4;
    const int2 id = ((const int2*)index)[cp + p];
    const ushort8 uv = *(const ushort8*)(Uc + (size_t)id.x * KC + l16 * 8);
    const ushort8 ev = *(const ushort8*)(Ec + (size_t)id.y * FD + l16 * 8);
    float s = 0.f;
#pragma unroll
    for (int q = 0; q < 8; q++) s += bf2f(uv[q]) * bf2f(ev[q]);
    s += __shfl_xor(s, 8, 64);
    s += __shfl_xor(s, 4, 64);
    s += __shfl_xor(s, 2, 64);
    s += __shfl_xor(s, 1, 64);
    if (l16 == 0) {
      float* op = out + cp + p;
      if (first) *op = s; else *op += s;
    }
  }
}

// ---- fallback (tiny workspace): direct fp32, slow but correct ----
__global__ __launch_bounds__(256) void naive_k(const float* __restrict__ emb,
                                               const int* __restrict__ index,
                                               const float* __restrict__ W,
                                               const float* __restrict__ wl,
                                               float* __restrict__ out) {
  __shared__ float bs[FD];
  __shared__ float red[256];
  const int c = blockIdx.y, p = blockIdx.x;
  const int i0 = index[((size_t)c * NPAIRS + p) * 2];
  const int i1 = index[((size_t)c * NPAIRS + p) * 2 + 1];
  const float* wlc = wl + (size_t)c * FD;
  for (int k = threadIdx.x; k < FD; k += 256) bs[k] = emb[(size_t)i1 * FD + k] * wlc[k];
  __syncthreads();
  float s = 0.f;
  for (int n = threadIdx.x; n < FD; n += 256) {
    const float* wr = W + (size_t)n * FD;
    float tacc = 0.f;
    for (int k = 0; k < FD; k++) tacc += wr[k] * bs[k];
    s += tacc * emb[(size_t)i0 * FD + n] * wlc[n];
  }
  red[threadIdx.x] = s;
  __syncthreads();
  for (int st = 128; st > 0; st >>= 1) {
    if (threadIdx.x < st) red[threadIdx.x] += red[threadIdx.x + st];
    __syncthreads();
  }
  if (threadIdx.x == 0) out[(size_t)c * NPAIRS + p] = red[0];
}

extern "C" void kernel_launch(void* const* d_in, const int* in_sizes, int n_in,
                              void* d_out, int out_size, void* d_ws, size_t ws_size,
                              hipStream_t stream) {
  const float* emb = (const float*)d_in[0];
  const int* index = (const int*)d_in[1];
  const float* Wg = (const float*)d_in[2];
  const float* wl = (const float*)d_in[3];
  float* out = (float*)d_out;

  const size_t ebytes = (size_t)NE * FD * 2;           // 4 MiB
  const size_t wtbytes = (size_t)NCELLS * FD * FD * 2; // 19.5 MiB
  const size_t ubytes = (size_t)NCELLS * NE * KC * 2;  // 39 MiB
  if (ws_size < ebytes + wtbytes + ubytes) {
    naive_k<<<dim3(NPAIRS, NCELLS), 256, 0, stream>>>(emb, index, Wg, wl, out);
    return;
  }

  unsigned short* Ebf = (unsigned short*)d_ws;
  unsigned short* Wt = (unsigned short*)((char*)d_ws + ebytes);
  unsigned short* U = (unsigned short*)((char*)d_ws + ebytes + wtbytes);

  conv_e<<<dim3((NE * FD / 4) / 256), 256, 0, stream>>>(emb, Ebf);
  prep_w<<<dim3(FD / 32, FD / 32, NCELLS), 256, 0, stream>>>(Wg, wl, Wt);
  for (int c = 0; c < FD / KC; c++) {
    const int kc0 = c * KC;
    gemm_k<<<dim3(NE / 128, NCELLS), 256, 0, stream>>>(Ebf, Wt, wl, U, kc0);
    dot_k<<<dim3(NPAIRS / 256, NCELLS), 256, 0, stream>>>(U, Ebf, index, out, kc0, c == 0);
  }
}

// Round 3
// 244.733 us; speedup vs baseline: 1.1430x; 1.1430x over previous
//
#include <hip/hip_runtime.h>
#include <stdint.h>

#define NE 4096
#define FD 512
#define NCELLS 39
#define NPAIRS 8192

typedef __attribute__((ext_vector_type(8))) short short8;
typedef __attribute__((ext_vector_type(8))) unsigned short ushort8;
typedef __attribute__((ext_vector_type(4))) float f32x4;

__device__ __forceinline__ unsigned short f2bf(float f) {
  union { float f; uint32_t u; } v; v.f = f;
  uint32_t u = v.u;
  return (unsigned short)((u + 0x7fffu + ((u >> 16) & 1u)) >> 16);  // RNE
}
__device__ __forceinline__ float bf2f(unsigned short b) {
  return __uint_as_float(((uint32_t)b) << 16);
}

__device__ __forceinline__ void async16(const void* g, void* l) {
  __builtin_amdgcn_global_load_lds((const __attribute__((address_space(1))) void*)g,
                                   (__attribute__((address_space(3))) void*)l, 16, 0, 0);
}

// ---- kernel 1: embedding fp32 -> bf16 ----
__global__ __launch_bounds__(256) void conv_e(const float* __restrict__ E,
                                              unsigned short* __restrict__ Ebf) {
  const int i = blockIdx.x * 256 + threadIdx.x;
  const float4 v = ((const float4*)E)[i];
  ushort4 o;
  o.x = f2bf(v.x); o.y = f2bf(v.y); o.z = f2bf(v.z); o.w = f2bf(v.w);
  ((ushort4*)Ebf)[i] = o;
}

// ---- kernel 2: Wt[ci][kout][n] = wl[c,n] * W[n,kout], bf16, transposed ----
__global__ __launch_bounds__(256) void prep_w(const float* __restrict__ W,
                                              const float* __restrict__ wl,
                                              unsigned short* __restrict__ Wt,
                                              int c0) {
  __shared__ float tile[32][33];
  const int ci = blockIdx.z;
  const int tn = blockIdx.x * 32, tk = blockIdx.y * 32;
  const int tx = threadIdx.x & 31, ty = threadIdx.x >> 5;
  const float* wlr = wl + (size_t)(c0 + ci) * FD;
#pragma unroll
  for (int i = 0; i < 4; i++) {
    int n = tn + ty + i * 8;
    tile[ty + i * 8][tx] = W[(size_t)n * FD + tk + tx] * wlr[n];
  }
  __syncthreads();
  unsigned short* dst = Wt + (size_t)ci * FD * FD;
#pragma unroll
  for (int i = 0; i < 4; i++) {
    int kout = tk + ty + i * 8;
    dst[(size_t)kout * FD + tn + tx] = f2bf(tile[tx][ty + i * 8]);
  }
}

// ---- kernel 3: U[ci][e][k] = wl[c,k] * sum_n Ebf[e,n] * Wt[ci][k][n]  (bf16 out) ----
// m97-style: 128x128 tile, BK=32, 4 waves (2x2), each wave 4x4 MFMA 16x16x32 tiles.
__global__ __launch_bounds__(256) void gemm_k(const unsigned short* __restrict__ Ebf,
                                              const unsigned short* __restrict__ Wt,
                                              const float* __restrict__ wl,
                                              unsigned short* __restrict__ U,
                                              int c0) {
  __shared__ unsigned short As[128 * 32];
  __shared__ unsigned short Bs[128 * 32];
  const int t = threadIdx.x;
  const int ci = blockIdx.z;
  const unsigned short* Ag = Ebf + (size_t)blockIdx.x * 128 * FD;
  const unsigned short* Bg = Wt + (size_t)ci * FD * FD + (size_t)blockIdx.y * 128 * FD;

  f32x4 acc[4][4];
#pragma unroll
  for (int i = 0; i < 4; i++)
#pragma unroll
    for (int j = 0; j < 4; j++) acc[i][j] = (f32x4){0.f, 0.f, 0.f, 0.f};

  const int wave = t >> 6, lane = t & 63;
  const int wm = (wave & 1) * 64, wn = (wave >> 1) * 64;
  const int lr = lane & 15, lq = lane >> 4;
  const int idx0 = t, idx1 = 256 + t;
  const int r0 = idx0 >> 2, cb0 = (idx0 & 3) * 8;
  const int r1 = idx1 >> 2, cb1 = (idx1 & 3) * 8;

  for (int k0 = 0; k0 < FD; k0 += 32) {
    async16(Ag + (size_t)r0 * FD + k0 + cb0, &As[idx0 * 8]);
    async16(Ag + (size_t)r1 * FD + k0 + cb1, &As[idx1 * 8]);
    async16(Bg + (size_t)r0 * FD + k0 + cb0, &Bs[idx0 * 8]);
    async16(Bg + (size_t)r1 * FD + k0 + cb1, &Bs[idx1 * 8]);
    __syncthreads();
    short8 af[4], bq[4];
#pragma unroll
    for (int mi = 0; mi < 4; mi++) af[mi] = *(const short8*)&As[(wm + mi * 16 + lr) * 32 + lq * 8];
#pragma unroll
    for (int ni = 0; ni < 4; ni++) bq[ni] = *(const short8*)&Bs[(wn + ni * 16 + lr) * 32 + lq * 8];
#pragma unroll
    for (int mi = 0; mi < 4; mi++)
#pragma unroll
      for (int ni = 0; ni < 4; ni++)
        acc[mi][ni] = __builtin_amdgcn_mfma_f32_16x16x32_bf16(af[mi], bq[ni], acc[mi][ni], 0, 0, 0);
    __syncthreads();
  }

  // epilogue: scale by wl[c, kout], store bf16.  C/D: col=lane&15, row=(lane>>4)*4+reg
  const float* wlr = wl + (size_t)(c0 + ci) * FD;
  unsigned short* Up = U + (size_t)ci * NE * FD;
  float wlv[4];
#pragma unroll
  for (int ni = 0; ni < 4; ni++) wlv[ni] = wlr[blockIdx.y * 128 + wn + ni * 16 + lr];
#pragma unroll
  for (int mi = 0; mi < 4; mi++) {
    int mbase = blockIdx.x * 128 + wm + mi * 16 + lq * 4;
#pragma unroll
    for (int ni = 0; ni < 4; ni++) {
      int n = blockIdx.y * 128 + wn + ni * 16 + lr;
#pragma unroll
      for (int r = 0; r < 4; r++) {
        Up[(size_t)(mbase + r) * FD + n] = f2bf(acc[mi][ni][r] * wlv[ni]);
      }
    }
  }
}

// ---- kernel 4: out[c,p] = sum_k U[ci,i0,k] * Ebf[i1,k] ----
// 16 lanes/pair, 4 pairs/wave-batch, 4 batches, 2-stage software pipeline.
__global__ __launch_bounds__(256) void dot_k(const unsigned short* __restrict__ U,
                                             const unsigned short* __restrict__ Ebf,
                                             const int* __restrict__ index,
                                             float* __restrict__ out,
                                             int c0) {
  const int ci = blockIdx.y;
  const int c = c0 + ci;
  const int wave = threadIdx.x >> 6, lane = threadIdx.x & 63;
  const int lg = lane >> 4, l16 = lane & 15;
  const unsigned short* Uc = U + (size_t)ci * NE * FD;
  const size_t cp = (size_t)c * NPAIRS;
  const int pb = blockIdx.x * 64 + wave * 16;

  int2 id[4];
#pragma unroll
  for (int b = 0; b < 4; b++) id[b] = ((const int2*)index)[cp + pb + b * 4 + lg];

  ushort8 uv[2][4], ev[2][4];
  {
    const unsigned short* ur = Uc + (size_t)id[0].x * FD + l16 * 8;
    const unsigned short* er = Ebf + (size_t)id[0].y * FD + l16 * 8;
#pragma unroll
    for (int r = 0; r < 4; r++) {
      uv[0][r] = *(const ushort8*)(ur + r * 128);
      ev[0][r] = *(const ushort8*)(er + r * 128);
    }
  }
#pragma unroll
  for (int b = 0; b < 4; b++) {
    const int cur = b & 1, nxt = cur ^ 1;
    if (b < 3) {
      const unsigned short* ur = Uc + (size_t)id[b + 1].x * FD + l16 * 8;
      const unsigned short* er = Ebf + (size_t)id[b + 1].y * FD + l16 * 8;
#pragma unroll
      for (int r = 0; r < 4; r++) {
        uv[nxt][r] = *(const ushort8*)(ur + r * 128);
        ev[nxt][r] = *(const ushort8*)(er + r * 128);
      }
    }
    float s = 0.f;
#pragma unroll
    for (int r = 0; r < 4; r++)
#pragma unroll
      for (int q = 0; q < 8; q++) s += bf2f(uv[cur][r][q]) * bf2f(ev[cur][r][q]);
    s += __shfl_xor(s, 1, 64);
    s += __shfl_xor(s, 2, 64);
    s += __shfl_xor(s, 4, 64);
    s += __shfl_xor(s, 8, 64);
    if (l16 == 0) out[cp + pb + b * 4 + lg] = s;
  }
}

// ---- fallback (tiny workspace): direct fp32, slow but correct ----
__global__ __launch_bounds__(256) void naive_k(const float* __restrict__ emb,
                                               const int* __restrict__ index,
                                               const float* __restrict__ W,
                                               const float* __restrict__ wl,
                                               float* __restrict__ out) {
  __shared__ float bs[FD];
  __shared__ float red[256];
  const int c = blockIdx.y, p = blockIdx.x;
  const int i0 = index[((size_t)c * NPAIRS + p) * 2];
  const int i1 = index[((size_t)c * NPAIRS + p) * 2 + 1];
  const float* wlc = wl + (size_t)c * FD;
  for (int k = threadIdx.x; k < FD; k += 256) bs[k] = emb[(size_t)i1 * FD + k] * wlc[k];
  __syncthreads();
  float s = 0.f;
  for (int n = threadIdx.x; n < FD; n += 256) {
    const float* wr = W + (size_t)n * FD;
    float tacc = 0.f;
    for (int k = 0; k < FD; k++) tacc += wr[k] * bs[k];
    s += tacc * emb[(size_t)i0 * FD + n] * wlc[n];
  }
  red[threadIdx.x] = s;
  __syncthreads();
  for (int st = 128; st > 0; st >>= 1) {
    if (threadIdx.x < st) red[threadIdx.x] += red[threadIdx.x + st];
    __syncthreads();
  }
  if (threadIdx.x == 0) out[(size_t)c * NPAIRS + p] = red[0];
}

extern "C" void kernel_launch(void* const* d_in, const int* in_sizes, int n_in,
                              void* d_out, int out_size, void* d_ws, size_t ws_size,
                              hipStream_t stream) {
  const float* emb = (const float*)d_in[0];
  const int* index = (const int*)d_in[1];
  const float* Wg = (const float*)d_in[2];
  const float* wl = (const float*)d_in[3];
  float* out = (float*)d_out;

  const size_t ebytes = (size_t)NE * FD * 2;  // 4 MiB bf16 embedding
  const size_t wtcell = (size_t)FD * FD * 2;  // 0.5 MiB per-cell Wt
  const size_t ucell = (size_t)NE * FD * 2;   // 4 MiB per-cell U
  size_t avail = ws_size > ebytes ? ws_size - ebytes : 0;
  int G = (int)(avail / (wtcell + ucell));
  if (G > NCELLS) G = NCELLS;

  if (G < 1) {
    naive_k<<<dim3(NPAIRS, NCELLS), 256, 0, stream>>>(emb, index, Wg, wl, out);
    return;
  }

  unsigned short* Ebf = (unsigned short*)d_ws;
  unsigned short* Wt = (unsigned short*)((char*)d_ws + ebytes);
  unsigned short* U = (unsigned short*)((char*)d_ws + ebytes + (size_t)G * wtcell);

  conv_e<<<dim3((NE * FD / 4) / 256), 256, 0, stream>>>(emb, Ebf);
  for (int c0 = 0; c0 < NCELLS; c0 += G) {
    int g = (NCELLS - c0 < G) ? (NCELLS - c0) : G;
    prep_w<<<dim3(FD / 32, FD / 32, g), 256, 0, stream>>>(Wg, wl, Wt, c0);
    gemm_k<<<dim3(NE / 128, FD / 128, g), 256, 0, stream>>>(Ebf, Wt, wl, U, c0);
    dot_k<<<dim3(NPAIRS / 64, g), 256, 0, stream>>>(U, Ebf, index, out, c0);
  }
}